// Round 1
// baseline (445.896 us; speedup 1.0000x reference)
//
#include <hip/hip_runtime.h>
#include <math.h>

// Problem dims (fixed)
#define B 32
#define S 512
#define Q 512
#define I 256
#define O 64
#define SIG_EPS 0.1f
#define LOG_SIG_EPS (-2.3025850929940457f)

// Workspace layout (in floats)
#define WS_L 0                         // 256*256
#define WS_LK (WS_L + 65536)           // 256*64
#define WS_M (WS_LK + 16384)           // B*256*256  (posterior_L -> inverse in place)
#define WS_RHS (WS_M + B * 65536)      // B*256*64
#define WS_D (WS_RHS + B * 16384)      // B*64*64
#define WS_PK (WS_D + B * 4096)        // B*256*64
#define WS_SP (WS_PK + B * 16384)      // B*512
#define WS_NLL (WS_SP + B * 512)       // 1

// Output layout
#define OUT_MU_ELEMS (B * Q * O)            // 1048576
#define OUT_SIG_ELEMS (B * Q * O * O)       // 67108864
#define OUT_NLL_IDX (OUT_MU_ELEMS + OUT_SIG_ELEMS)

__device__ __forceinline__ void fma4x4(const float4 av, const float4 bv, float acc[4][4]) {
  const float ar[4] = {av.x, av.y, av.z, av.w};
  const float br[4] = {bv.x, bv.y, bv.z, bv.w};
#pragma unroll
  for (int i = 0; i < 4; ++i)
#pragma unroll
    for (int j = 0; j < 4; ++j) acc[i][j] += ar[i] * br[j];
}

// ---------------- init: spread = 1.0, nll accumulator = 0 ----------------
__global__ __launch_bounds__(256) void k_init(float* spread, float* nllacc) {
  int i = blockIdx.x * 256 + threadIdx.x;
  if (i < B * Q) spread[i] = 1.0f;
  if (i == 0) nllacc[0] = 0.0f;
}

// ---------------- L = L_asym @ L_asym^T ----------------
__global__ __launch_bounds__(256) void k_L(const float* __restrict__ La, float* __restrict__ Lout) {
  int i = blockIdx.x;  // 256 blocks
  __shared__ float rowi[256];
  int t = threadIdx.x;
  rowi[t] = La[(size_t)i * 256 + t];
  __syncthreads();
  const float* rj = La + (size_t)t * 256;
  float s = 0.f;
#pragma unroll 4
  for (int kk = 0; kk < 256; ++kk) s += rowi[kk] * rj[kk];
  Lout[(size_t)i * 256 + t] = s;
}

// ---------------- LK = L @ K ----------------
__global__ __launch_bounds__(256) void k_LK(const float* __restrict__ Lm, const float* __restrict__ Km,
                                            float* __restrict__ LKo) {
  int idx = blockIdx.x * 256 + threadIdx.x;  // 16384
  int i = idx >> 6, o = idx & 63;
  const float* Lr = Lm + (size_t)i * 256;
  float s = 0.f;
#pragma unroll 4
  for (int j = 0; j < 256; ++j) s += Lr[j] * Km[(size_t)j * 64 + o];
  LKo[idx] = s;
}

// ---------------- gram (TN): M[b] = phi_s^T phi_s + L ; RHS[b] = phi_s^T y_s + LK ----------------
__global__ __launch_bounds__(256) void k_gram(const float* __restrict__ phi_s, const float* __restrict__ y_s,
                                              const float* __restrict__ Lm, const float* __restrict__ LKm,
                                              float* __restrict__ M, float* __restrict__ RHS) {
  int b = blockIdx.x, it = blockIdx.y, jt = blockIdx.z;
  int i0 = it * 64, j0 = jt * 64;
  const float* Pb = phi_s + (size_t)b * S * I;
  bool isY = (j0 >= 256);
  const float* Wb = isY ? (y_s + (size_t)b * S * O) : Pb;
  int wstride = isY ? O : I;
  int wcol = isY ? 0 : j0;

  __shared__ float Ps[16][64];
  __shared__ float Ws[16][64];
  float acc[4][4] = {};
  int t = threadIdx.x;
  int tr = t >> 4, tc = t & 15;
  int lr = t >> 6, lc = t & 63;

  for (int ks = 0; ks < S; ks += 16) {
    __syncthreads();
#pragma unroll
    for (int m = 0; m < 4; ++m) {
      Ps[lr + 4 * m][lc] = Pb[(size_t)(ks + lr + 4 * m) * I + i0 + lc];
      Ws[lr + 4 * m][lc] = Wb[(size_t)(ks + lr + 4 * m) * wstride + wcol + lc];
    }
    __syncthreads();
#pragma unroll
    for (int kk = 0; kk < 16; ++kk) {
      float4 av = *(const float4*)&Ps[kk][tr * 4];
      float4 bv = *(const float4*)&Ws[kk][tc * 4];
      fma4x4(av, bv, acc);
    }
  }

#pragma unroll
  for (int mi = 0; mi < 4; ++mi) {
    int i = i0 + tr * 4 + mi;
    if (!isY) {
      int j = j0 + tc * 4;
      float4 add = *(const float4*)&Lm[(size_t)i * 256 + j];
      float4 v = {acc[mi][0] + add.x, acc[mi][1] + add.y, acc[mi][2] + add.z, acc[mi][3] + add.w};
      *(float4*)&M[((size_t)b * 256 + i) * 256 + j] = v;
    } else {
      int j = tc * 4;  // 0..63 within RHS
      float4 add = *(const float4*)&LKm[(size_t)i * 64 + j];
      float4 v = {acc[mi][0] + add.x, acc[mi][1] + add.y, acc[mi][2] + add.z, acc[mi][3] + add.w};
      *(float4*)&RHS[((size_t)b * 256 + i) * 64 + j] = v;
    }
  }
}

// ---------------- invert 64x64 diagonal block (register GJ) -> Dbuf ----------------
__global__ __launch_bounds__(256) void k_inv64(const float* __restrict__ M, float* __restrict__ Dbuf, int k) {
  int b = blockIdx.x;
  const float* Mb = M + (size_t)b * 65536;
  int t = threadIdx.x;
  int r = t >> 2, q = t & 3;
  float a[16], im[16];
  __shared__ float colbuf[64];
  __shared__ float rowA[64];
  __shared__ float rowI[64];
#pragma unroll
  for (int c = 0; c < 16; ++c) a[c] = Mb[(size_t)(k * 64 + r) * 256 + k * 64 + q * 16 + c];
#pragma unroll
  for (int c = 0; c < 16; ++c) im[c] = ((q * 16 + c) == r) ? 1.0f : 0.0f;

  for (int p = 0; p < 64; ++p) {
    int pq = p >> 4, pc = p & 15;
    if (q == pq) colbuf[r] = a[pc];
    __syncthreads();
    float pivinv = 1.0f / colbuf[p];
    if (r == p) {
#pragma unroll
      for (int c = 0; c < 16; ++c) {
        a[c] *= pivinv;
        im[c] *= pivinv;
        rowA[q * 16 + c] = a[c];
        rowI[q * 16 + c] = im[c];
      }
    }
    __syncthreads();
    if (r != p) {
      float f = colbuf[r];
#pragma unroll
      for (int c = 0; c < 16; ++c) {
        a[c] -= f * rowA[q * 16 + c];
        im[c] -= f * rowI[q * 16 + c];
      }
    }
    __syncthreads();
  }
#pragma unroll
  for (int c = 0; c < 16; ++c) Dbuf[(size_t)b * 4096 + (size_t)r * 64 + q * 16 + c] = im[c];
}

// ---------------- GJ row scale: M_kj <- D @ M_kj (j != k) ; M_kk <- D ----------------
__global__ __launch_bounds__(256) void k_rowscale(float* __restrict__ M, const float* __restrict__ Dbuf, int k) {
  int b = blockIdx.x, j = blockIdx.y;
  float* Mb = M + (size_t)b * 65536;
  const float* D = Dbuf + (size_t)b * 4096;
  int t = threadIdx.x;
  if (j == k) {
    for (int m = 0; m < 16; ++m) {
      int idx = t + m * 256;
      int r = idx >> 6, c = idx & 63;
      Mb[(size_t)(k * 64 + r) * 256 + k * 64 + c] = D[idx];
    }
    return;
  }
  __shared__ float Dt[64][64];  // Dt[m][r] = D[r][m]
  __shared__ float Xs[64][64];  // Xs[m][c] = M_kj[m][c]
#pragma unroll
  for (int p = 0; p < 4; ++p) {
    int cc = (t & 3) * 4 + p * 16;
    float4 dv = *(const float4*)&D[(size_t)(t >> 2) * 64 + cc];
    Dt[cc + 0][t >> 2] = dv.x;
    Dt[cc + 1][t >> 2] = dv.y;
    Dt[cc + 2][t >> 2] = dv.z;
    Dt[cc + 3][t >> 2] = dv.w;
  }
  for (int m = 0; m < 16; ++m) {
    int idx = t + m * 256;
    int r = idx >> 6, c = idx & 63;
    Xs[r][c] = Mb[(size_t)(k * 64 + r) * 256 + j * 64 + c];
  }
  __syncthreads();
  float acc[4][4] = {};
  int tr = t >> 4, tc = t & 15;
#pragma unroll 4
  for (int m = 0; m < 64; ++m) {
    float4 av = *(const float4*)&Dt[m][tr * 4];
    float4 bv = *(const float4*)&Xs[m][tc * 4];
    fma4x4(av, bv, acc);
  }
#pragma unroll
  for (int mi = 0; mi < 4; ++mi) {
    float4 v = {acc[mi][0], acc[mi][1], acc[mi][2], acc[mi][3]};
    *(float4*)&Mb[(size_t)(k * 64 + tr * 4 + mi) * 256 + j * 64 + tc * 4] = v;
  }
}

// ---------------- GJ update: for i!=k: M_ij -= M_ik @ M_kj (j!=k), M_ik <- -M_ik @ D ----------------
__global__ __launch_bounds__(256) void k_update(float* __restrict__ M, const float* __restrict__ Dbuf, int k) {
  int b = blockIdx.x;
  int iblk = blockIdx.y + (blockIdx.y >= k ? 1 : 0);
  float* Mb = M + (size_t)b * 65536;
  const float* D = Dbuf + (size_t)b * 4096;
  int t = threadIdx.x;
  int tr = t >> 4, tc = t & 15;

  __shared__ float Et[64][64];  // Et[m][r] = M_ik[r][m] (old)
  __shared__ float Xs[64][64];
#pragma unroll
  for (int p = 0; p < 4; ++p) {
    int cc = (t & 3) * 4 + p * 16;
    float4 ev = *(const float4*)&Mb[(size_t)(iblk * 64 + (t >> 2)) * 256 + k * 64 + cc];
    Et[cc + 0][t >> 2] = ev.x;
    Et[cc + 1][t >> 2] = ev.y;
    Et[cc + 2][t >> 2] = ev.z;
    Et[cc + 3][t >> 2] = ev.w;
  }
  for (int j = 0; j < 4; ++j) {
    __syncthreads();
    for (int m = 0; m < 16; ++m) {
      int idx = t + m * 256;
      int r = idx >> 6, c = idx & 63;
      Xs[r][c] = (j == k) ? D[idx] : Mb[(size_t)(k * 64 + r) * 256 + j * 64 + c];
    }
    __syncthreads();
    float acc[4][4] = {};
#pragma unroll 4
    for (int m = 0; m < 64; ++m) {
      float4 av = *(const float4*)&Et[m][tr * 4];
      float4 bv = *(const float4*)&Xs[m][tc * 4];
      fma4x4(av, bv, acc);
    }
#pragma unroll
    for (int mi = 0; mi < 4; ++mi) {
      size_t off = (size_t)(iblk * 64 + tr * 4 + mi) * 256 + j * 64 + tc * 4;
      if (j == k) {
        float4 v = {-acc[mi][0], -acc[mi][1], -acc[mi][2], -acc[mi][3]};
        *(float4*)&Mb[off] = v;
      } else {
        float4 old = *(const float4*)&Mb[off];
        float4 v = {old.x - acc[mi][0], old.y - acc[mi][1], old.z - acc[mi][2], old.w - acc[mi][3]};
        *(float4*)&Mb[off] = v;
      }
    }
  }
}

// ---------------- NN GEMM: postK[b] = Minv[b] @ RHS[b]  (256x256 * 256x64) ----------------
__global__ __launch_bounds__(256) void k_postK(const float* __restrict__ Minv, const float* __restrict__ RHS,
                                               float* __restrict__ PK) {
  int b = blockIdx.x, it = blockIdx.y;
  int i0 = it * 64;
  const float* A = Minv + (size_t)b * 65536;
  const float* Bm = RHS + (size_t)b * 16384;
  __shared__ float At[16][64];  // At[kk][i]
  __shared__ float Bs[16][64];
  float acc[4][4] = {};
  int t = threadIdx.x, tr = t >> 4, tc = t & 15;
  int ar = t >> 2, ac4 = (t & 3) * 4;
  int br = t >> 6, bc = t & 63;
  for (int ks = 0; ks < 256; ks += 16) {
    __syncthreads();
    float4 av = *(const float4*)&A[(size_t)(i0 + ar) * 256 + ks + ac4];
    At[ac4 + 0][ar] = av.x;
    At[ac4 + 1][ar] = av.y;
    At[ac4 + 2][ar] = av.z;
    At[ac4 + 3][ar] = av.w;
#pragma unroll
    for (int m = 0; m < 4; ++m) Bs[br + 4 * m][bc] = Bm[(size_t)(ks + br + 4 * m) * 64 + bc];
    __syncthreads();
#pragma unroll
    for (int kk = 0; kk < 16; ++kk) {
      float4 a4 = *(const float4*)&At[kk][tr * 4];
      float4 b4 = *(const float4*)&Bs[kk][tc * 4];
      fma4x4(a4, b4, acc);
    }
  }
#pragma unroll
  for (int mi = 0; mi < 4; ++mi) {
    float4 v = {acc[mi][0], acc[mi][1], acc[mi][2], acc[mi][3]};
    *(float4*)&PK[(size_t)b * 16384 + (size_t)(i0 + tr * 4 + mi) * 64 + tc * 4] = v;
  }
}

// ---------------- NN GEMM: mu[b] = phi_q[b] @ postK[b]  (512x256 * 256x64) -> d_out ----------------
__global__ __launch_bounds__(256) void k_mu(const float* __restrict__ phi_q, const float* __restrict__ PK,
                                            float* __restrict__ mu) {
  int b = blockIdx.x, it = blockIdx.y;
  int i0 = it * 64;
  const float* A = phi_q + (size_t)b * Q * I;
  const float* Bm = PK + (size_t)b * 16384;
  __shared__ float At[16][64];
  __shared__ float Bs[16][64];
  float acc[4][4] = {};
  int t = threadIdx.x, tr = t >> 4, tc = t & 15;
  int ar = t >> 2, ac4 = (t & 3) * 4;
  int br = t >> 6, bc = t & 63;
  for (int ks = 0; ks < 256; ks += 16) {
    __syncthreads();
    float4 av = *(const float4*)&A[(size_t)(i0 + ar) * 256 + ks + ac4];
    At[ac4 + 0][ar] = av.x;
    At[ac4 + 1][ar] = av.y;
    At[ac4 + 2][ar] = av.z;
    At[ac4 + 3][ar] = av.w;
#pragma unroll
    for (int m = 0; m < 4; ++m) Bs[br + 4 * m][bc] = Bm[(size_t)(ks + br + 4 * m) * 64 + bc];
    __syncthreads();
#pragma unroll
    for (int kk = 0; kk < 16; ++kk) {
      float4 a4 = *(const float4*)&At[kk][tr * 4];
      float4 b4 = *(const float4*)&Bs[kk][tc * 4];
      fma4x4(a4, b4, acc);
    }
  }
#pragma unroll
  for (int mi = 0; mi < 4; ++mi) {
    float4 v = {acc[mi][0], acc[mi][1], acc[mi][2], acc[mi][3]};
    *(float4*)&mu[(size_t)b * Q * O + (size_t)(i0 + tr * 4 + mi) * 64 + tc * 4] = v;
  }
}

// ---------------- spread: X = phi_q @ Minv, spread += rowsum(X .* phi_q) ----------------
__global__ __launch_bounds__(256) void k_spread(const float* __restrict__ phi_q, const float* __restrict__ Minv,
                                                float* __restrict__ spread) {
  int b = blockIdx.x, it = blockIdx.y, jt = blockIdx.z;
  int q0 = it * 64, j0 = jt * 64;
  const float* A = phi_q + (size_t)b * Q * I;
  const float* Bm = Minv + (size_t)b * 65536;
  __shared__ float At[16][64];
  __shared__ float Bs[16][64];
  float acc[4][4] = {};
  int t = threadIdx.x, tr = t >> 4, tc = t & 15;
  int ar = t >> 2, ac4 = (t & 3) * 4;
  int br = t >> 6, bc = t & 63;
  for (int ks = 0; ks < 256; ks += 16) {
    __syncthreads();
    float4 av = *(const float4*)&A[(size_t)(q0 + ar) * 256 + ks + ac4];
    At[ac4 + 0][ar] = av.x;
    At[ac4 + 1][ar] = av.y;
    At[ac4 + 2][ar] = av.z;
    At[ac4 + 3][ar] = av.w;
#pragma unroll
    for (int m = 0; m < 4; ++m) Bs[br + 4 * m][bc] = Bm[(size_t)(ks + br + 4 * m) * 256 + j0 + bc];
    __syncthreads();
#pragma unroll
    for (int kk = 0; kk < 16; ++kk) {
      float4 a4 = *(const float4*)&At[kk][tr * 4];
      float4 b4 = *(const float4*)&Bs[kk][tc * 4];
      fma4x4(a4, b4, acc);
    }
  }
  float rs[4];
#pragma unroll
  for (int mi = 0; mi < 4; ++mi) {
    int qrow = q0 + tr * 4 + mi;
    float4 pv = *(const float4*)&A[(size_t)qrow * 256 + j0 + tc * 4];
    rs[mi] = acc[mi][0] * pv.x + acc[mi][1] * pv.y + acc[mi][2] * pv.z + acc[mi][3] * pv.w;
  }
#pragma unroll
  for (int off = 1; off < 16; off <<= 1) {
#pragma unroll
    for (int mi = 0; mi < 4; ++mi) rs[mi] += __shfl_xor(rs[mi], off);
  }
  if (tc == 0) {
#pragma unroll
    for (int mi = 0; mi < 4; ++mi) atomicAdd(&spread[(size_t)b * Q + q0 + tr * 4 + mi], rs[mi]);
  }
}

// ---------------- sig_pred fill: diag = spread * 0.1 ----------------
__global__ __launch_bounds__(256) void k_sigfill(const float* __restrict__ spread, float4* __restrict__ sig) {
  size_t idx = (size_t)blockIdx.x * 256 + threadIdx.x;  // float4 index
  if (idx >= (size_t)OUT_SIG_ELEMS / 4) return;
  int p4 = (int)(idx & 15);
  int o = (int)((idx >> 4) & 63);
  size_t bq = idx >> 10;
  float4 v = {0.f, 0.f, 0.f, 0.f};
  if (p4 == (o >> 2)) {
    float sval = spread[bq] * SIG_EPS;
    ((float*)&v)[o & 3] = sval;
  }
  sig[idx] = v;
}

// ---------------- nll ----------------
__global__ __launch_bounds__(256) void k_nll(const float* __restrict__ yq, const float* __restrict__ mu,
                                             const float* __restrict__ spread, float* __restrict__ nllacc) {
  int bq = blockIdx.x * 256 + threadIdx.x;  // 0..16383
  float sp = spread[bq];
  const float4* yv = (const float4*)(yq + (size_t)bq * 64);
  const float4* mv = (const float4*)(mu + (size_t)bq * 64);
  float ssd = 0.f;
#pragma unroll
  for (int i = 0; i < 16; ++i) {
    float4 a = yv[i], b = mv[i];
    float dx = a.x - b.x, dy = a.y - b.y, dz = a.z - b.z, dw = a.w - b.w;
    ssd += dx * dx + dy * dy + dz * dz + dw * dw;
  }
  float quadf = ssd / (sp * SIG_EPS);
  float ld = 64.0f * (logf(sp) + LOG_SIG_EPS);
  float val = (ld + quadf) * (1.0f / 16384.0f);
#pragma unroll
  for (int off = 32; off; off >>= 1) val += __shfl_down(val, off);
  if ((threadIdx.x & 63) == 0) atomicAdd(nllacc, val);
}

__global__ void k_fin(const float* __restrict__ nllacc, float* __restrict__ out) {
  if (threadIdx.x == 0 && blockIdx.x == 0) out[0] = nllacc[0];
}

extern "C" void kernel_launch(void* const* d_in, const int* in_sizes, int n_in, void* d_out, int out_size,
                              void* d_ws, size_t ws_size, hipStream_t stream) {
  const float* phi_s = (const float*)d_in[0];
  const float* y_s = (const float*)d_in[1];
  const float* phi_q = (const float*)d_in[2];
  const float* y_q = (const float*)d_in[3];
  const float* Km = (const float*)d_in[4];
  const float* La = (const float*)d_in[5];

  float* ws = (float*)d_ws;
  float* Lm = ws + WS_L;
  float* LKm = ws + WS_LK;
  float* Mbuf = ws + WS_M;
  float* RHSb = ws + WS_RHS;
  float* Dbuf = ws + WS_D;
  float* PKb = ws + WS_PK;
  float* spread = ws + WS_SP;
  float* nllacc = ws + WS_NLL;

  float* out_mu = (float*)d_out;
  float* out_sig = out_mu + OUT_MU_ELEMS;
  float* out_nll = out_mu + OUT_NLL_IDX;

  k_init<<<64, 256, 0, stream>>>(spread, nllacc);
  k_L<<<256, 256, 0, stream>>>(La, Lm);
  k_LK<<<64, 256, 0, stream>>>(Lm, Km, LKm);
  k_gram<<<dim3(B, 4, 5), 256, 0, stream>>>(phi_s, y_s, Lm, LKm, Mbuf, RHSb);
  for (int k = 0; k < 4; ++k) {
    k_inv64<<<B, 256, 0, stream>>>(Mbuf, Dbuf, k);
    k_rowscale<<<dim3(B, 4), 256, 0, stream>>>(Mbuf, Dbuf, k);
    k_update<<<dim3(B, 3), 256, 0, stream>>>(Mbuf, Dbuf, k);
  }
  k_postK<<<dim3(B, 4), 256, 0, stream>>>(Mbuf, RHSb, PKb);
  k_mu<<<dim3(B, 8), 256, 0, stream>>>(phi_q, PKb, out_mu);
  k_spread<<<dim3(B, 8, 4), 256, 0, stream>>>(phi_q, Mbuf, spread);
  k_sigfill<<<OUT_SIG_ELEMS / 4 / 256, 256, 0, stream>>>(spread, (float4*)out_sig);
  k_nll<<<64, 256, 0, stream>>>(y_q, out_mu, spread, nllacc);
  k_fin<<<1, 64, 0, stream>>>(nllacc, out_nll);
}

// Round 2
// 330.051 us; speedup vs baseline: 1.3510x; 1.3510x over previous
//
#include <hip/hip_runtime.h>
#include <math.h>

#define B 32
#define S 512
#define Q 512
#define I 256
#define O 64
#define SIG_EPS 0.1f
#define LOG_SIG_EPS (-2.3025850929940457f)

// Workspace layout (floats)
#define WS_L 0                          // 65536
#define WS_T1 (WS_L + 65536)            // 16384   T1 = La^T @ K
#define WS_LK (WS_T1 + 16384)           // 16384   LK = La @ T1 = L @ K
#define WS_M (WS_LK + 16384)            // B*65536 posterior_L -> inverse in place
#define WS_RHS (WS_M + B * 65536)       // B*16384 phi^T y (LK added later)
#define WS_D (WS_RHS + B * 16384)       // 2*B*4096 double-buffered diag inverses
#define WS_PK (WS_D + 2 * B * 4096)     // B*16384
#define WS_SP (WS_PK + B * 16384)       // B*512
#define WS_NLL (WS_SP + B * 512)        // 1

#define OUT_MU_ELEMS (B * Q * O)
#define OUT_SIG_ELEMS (B * Q * O * O)
#define OUT_NLL_IDX (OUT_MU_ELEMS + OUT_SIG_ELEMS)

__device__ __forceinline__ void fma4x4(const float4 av, const float4 bv, float acc[4][4]) {
  const float ar[4] = {av.x, av.y, av.z, av.w};
  const float br[4] = {bv.x, bv.y, bv.z, bv.w};
#pragma unroll
  for (int i = 0; i < 4; ++i)
#pragma unroll
    for (int j = 0; j < 4; ++j) acc[i][j] += ar[i] * br[j];
}

// 64x64 tile loaders (256 threads)
__device__ __forceinline__ void load_direct64(float* dst, int ds, const float* src, int ss, int t) {
#pragma unroll
  for (int m = 0; m < 4; ++m) {
    int r = (t >> 4) + 16 * m, c4 = (t & 15) * 4;
    *(float4*)&dst[r * ds + c4] = *(const float4*)&src[(size_t)r * ss + c4];
  }
}
__device__ __forceinline__ void load_trans64(float* dst, int ds /*68*/, const float* src, int ss, int t) {
#pragma unroll
  for (int m = 0; m < 4; ++m) {
    int r = (t >> 4) + 16 * m, c4 = (t & 15) * 4;
    float4 v = *(const float4*)&src[(size_t)r * ss + c4];
    dst[(c4 + 0) * ds + r] = v.x;
    dst[(c4 + 1) * ds + r] = v.y;
    dst[(c4 + 2) * ds + r] = v.z;
    dst[(c4 + 3) * ds + r] = v.w;
  }
}
// C(64x64) = A*B, A in At[kk][r] (stride SA), B in Bs[kk][c] (stride SB)
template <int SA, int SB>
__device__ __forceinline__ void gemm64(const float* At, const float* Bs, int tr, int tc, float acc[4][4]) {
#pragma unroll 8
  for (int kk = 0; kk < 64; ++kk) {
    float4 a = *(const float4*)&At[kk * SA + tr * 4];
    float4 b = *(const float4*)&Bs[kk * SB + tc * 4];
    fma4x4(a, b, acc);
  }
}

#define SC4(V) \
  V.x *= pivinv; V.y *= pivinv; V.z *= pivinv; V.w *= pivinv
#define UP4(V, R) \
  V.x -= g * R.x; V.y -= g * R.y; V.z -= g * R.z; V.w -= g * R.w

// Gauss-Jordan inverse of 64x64 SPD tile in LDS (stride TS), 256 threads.
// One barrier per pivot: publish RAW pivot row (double-buffered), f via intra-wave shfl.
// rowbuf: 256 floats LDS. Result written to Dout (global, 64x64 row-major).
template <int TS>
__device__ void gj64(const float* T, float* rowbuf, float* Dout, int t) {
  int r = t >> 2, q = t & 3;
  int lane = t & 63;
  float4 A0 = *(const float4*)&T[r * TS + q * 16 + 0];
  float4 A1 = *(const float4*)&T[r * TS + q * 16 + 4];
  float4 A2 = *(const float4*)&T[r * TS + q * 16 + 8];
  float4 A3 = *(const float4*)&T[r * TS + q * 16 + 12];
#define IC(c) (((q * 16 + (c)) == r) ? 1.f : 0.f)
  float4 I0 = make_float4(IC(0), IC(1), IC(2), IC(3));
  float4 I1 = make_float4(IC(4), IC(5), IC(6), IC(7));
  float4 I2 = make_float4(IC(8), IC(9), IC(10), IC(11));
  float4 I3 = make_float4(IC(12), IC(13), IC(14), IC(15));
#undef IC
  for (int p = 0; p < 64; ++p) {
    float* RA = rowbuf + (p & 1) * 128;
    float* RI = RA + 64;
    if (r == p) {
      ((float4*)&RA[q * 16])[0] = A0; ((float4*)&RA[q * 16])[1] = A1;
      ((float4*)&RA[q * 16])[2] = A2; ((float4*)&RA[q * 16])[3] = A3;
      ((float4*)&RI[q * 16])[0] = I0; ((float4*)&RI[q * 16])[1] = I1;
      ((float4*)&RI[q * 16])[2] = I2; ((float4*)&RI[q * 16])[3] = I3;
    }
    __syncthreads();
    float pivinv = 1.0f / RA[p];
    // extract this thread's element in column p (p is uniform -> uniform branches)
    int s = p & 15;
    float4 blk = (s < 8) ? ((s < 4) ? A0 : A1) : ((s < 12) ? A2 : A3);
    int sc = s & 3;
    float ap = (sc == 0) ? blk.x : (sc == 1) ? blk.y : (sc == 2) ? blk.z : blk.w;
    float f = __shfl(ap, (lane & ~3) | (p >> 4), 64);
    float4 ra0 = ((const float4*)&RA[q * 16])[0], ra1 = ((const float4*)&RA[q * 16])[1];
    float4 ra2 = ((const float4*)&RA[q * 16])[2], ra3 = ((const float4*)&RA[q * 16])[3];
    float4 ri0 = ((const float4*)&RI[q * 16])[0], ri1 = ((const float4*)&RI[q * 16])[1];
    float4 ri2 = ((const float4*)&RI[q * 16])[2], ri3 = ((const float4*)&RI[q * 16])[3];
    if (r == p) {
      SC4(A0); SC4(A1); SC4(A2); SC4(A3);
      SC4(I0); SC4(I1); SC4(I2); SC4(I3);
    } else {
      float g = f * pivinv;
      UP4(A0, ra0); UP4(A1, ra1); UP4(A2, ra2); UP4(A3, ra3);
      UP4(I0, ri0); UP4(I1, ri1); UP4(I2, ri2); UP4(I3, ri3);
    }
  }
  ((float4*)&Dout[r * 64 + q * 16])[0] = I0;
  ((float4*)&Dout[r * 64 + q * 16])[1] = I1;
  ((float4*)&Dout[r * 64 + q * 16])[2] = I2;
  ((float4*)&Dout[r * 64 + q * 16])[3] = I3;
}

// ---------------- pre1: init + L = La La^T (16 tiles) + T1 = La^T K (4 tiles) ----------------
__global__ __launch_bounds__(256) void k_pre1(const float* __restrict__ La, const float* __restrict__ Km,
                                              float* __restrict__ Lm, float* __restrict__ T1,
                                              float* __restrict__ spread, float* __restrict__ nllacc) {
  __shared__ float sA[16 * 68];
  __shared__ float sB[16 * 68];
  int blk = blockIdx.x, t = threadIdx.x;
  if (blk >= 20) {
    int idx = (blk - 20) * 256 + t;
    spread[idx] = 1.0f;
    if (idx == 0) nllacc[0] = 0.f;
    return;
  }
  int tr = t >> 4, tc = t & 15;
  float acc[4][4] = {};
  if (blk < 16) {
    int i0 = (blk >> 2) * 64, j0 = (blk & 3) * 64;
    for (int ks = 0; ks < 256; ks += 16) {
      __syncthreads();
#pragma unroll
      for (int m = 0; m < 4; ++m) {
        int r = (t >> 4) + 16 * m, kk = t & 15;
        sA[kk * 68 + r] = La[(size_t)(i0 + r) * 256 + ks + kk];
        sB[kk * 68 + r] = La[(size_t)(j0 + r) * 256 + ks + kk];
      }
      __syncthreads();
#pragma unroll
      for (int kk = 0; kk < 16; ++kk) {
        float4 a = *(const float4*)&sA[kk * 68 + tr * 4];
        float4 bv = *(const float4*)&sB[kk * 68 + tc * 4];
        fma4x4(a, bv, acc);
      }
    }
#pragma unroll
    for (int mi = 0; mi < 4; ++mi) {
      float4 v = {acc[mi][0], acc[mi][1], acc[mi][2], acc[mi][3]};
      *(float4*)&Lm[(size_t)(i0 + tr * 4 + mi) * 256 + j0 + tc * 4] = v;
    }
  } else {
    int i0 = (blk - 16) * 64;
    for (int ks = 0; ks < 256; ks += 16) {
      __syncthreads();
#pragma unroll
      for (int m = 0; m < 4; ++m) {
        int kk = (t >> 6) + 4 * m, c = t & 63;
        sA[kk * 68 + c] = La[(size_t)(ks + kk) * 256 + i0 + c];
        sB[kk * 68 + c] = Km[(size_t)(ks + kk) * 64 + c];
      }
      __syncthreads();
#pragma unroll
      for (int kk = 0; kk < 16; ++kk) {
        float4 a = *(const float4*)&sA[kk * 68 + tr * 4];
        float4 bv = *(const float4*)&sB[kk * 68 + tc * 4];
        fma4x4(a, bv, acc);
      }
    }
#pragma unroll
    for (int mi = 0; mi < 4; ++mi) {
      float4 v = {acc[mi][0], acc[mi][1], acc[mi][2], acc[mi][3]};
      *(float4*)&T1[(size_t)(i0 + tr * 4 + mi) * 64 + tc * 4] = v;
    }
  }
}

// ---------------- gram: M (10 sym tiles + mirror) + RHS (4) + LK (4 global) + D0 GJ fold ----------------
__global__ __launch_bounds__(256) void k_gram(const float* __restrict__ phi_s, const float* __restrict__ y_s,
                                              const float* __restrict__ Lm, const float* __restrict__ La,
                                              const float* __restrict__ T1, float* __restrict__ M,
                                              float* __restrict__ RHS, float* __restrict__ LK,
                                              float* __restrict__ Dbuf) {
  __shared__ float Ps[16][64];
  __shared__ float Ws[16][64];
  __shared__ float trbuf[64 * 68];
  __shared__ float rowbuf[256];
  int b = blockIdx.x, y = blockIdx.y;
  int t = threadIdx.x;
  int tr = t >> 4, tc = t & 15;
  float acc[4][4] = {};

  if (y == 14) {
    if (b >= 4) return;  // LK: 4 tiles total
    int i0 = b * 64;
    for (int ks = 0; ks < 256; ks += 16) {
      __syncthreads();
#pragma unroll
      for (int m = 0; m < 4; ++m) {
        trbuf[(t & 15) * 68 + (t >> 4) + 16 * m] = La[(size_t)(i0 + (t >> 4) + 16 * m) * 256 + ks + (t & 15)];
        Ws[(t >> 6) + 4 * m][t & 63] = T1[(size_t)(ks + (t >> 6) + 4 * m) * 64 + (t & 63)];
      }
      __syncthreads();
#pragma unroll
      for (int kk = 0; kk < 16; ++kk) {
        float4 a = *(const float4*)&trbuf[kk * 68 + tr * 4];
        float4 bv = *(const float4*)&Ws[kk][tc * 4];
        fma4x4(a, bv, acc);
      }
    }
#pragma unroll
    for (int mi = 0; mi < 4; ++mi) {
      float4 v = {acc[mi][0], acc[mi][1], acc[mi][2], acc[mi][3]};
      *(float4*)&LK[(size_t)(i0 + tr * 4 + mi) * 64 + tc * 4] = v;
    }
    return;
  }

  const int TI[10] = {0, 0, 0, 0, 1, 1, 1, 2, 2, 3};
  const int TJ[10] = {0, 1, 2, 3, 1, 2, 3, 2, 3, 3};
  bool isRHS = (y >= 10);
  int it = isRHS ? (y - 10) : TI[y];
  int jt = isRHS ? 0 : TJ[y];
  int i0 = it * 64, j0 = jt * 64;
  const float* Pb = phi_s + (size_t)b * S * I;
  const float* Wb = isRHS ? (y_s + (size_t)b * S * O) : Pb;
  int wstride = isRHS ? O : I;
  int wcol = isRHS ? 0 : j0;
  int lr = t >> 6, lc = t & 63;
  for (int ks = 0; ks < S; ks += 16) {
    __syncthreads();
#pragma unroll
    for (int m = 0; m < 4; ++m) {
      Ps[lr + 4 * m][lc] = Pb[(size_t)(ks + lr + 4 * m) * I + i0 + lc];
      Ws[lr + 4 * m][lc] = Wb[(size_t)(ks + lr + 4 * m) * wstride + wcol + lc];
    }
    __syncthreads();
#pragma unroll
    for (int kk = 0; kk < 16; ++kk) {
      float4 a = *(const float4*)&Ps[kk][tr * 4];
      float4 bv = *(const float4*)&Ws[kk][tc * 4];
      fma4x4(a, bv, acc);
    }
  }
  float* Mb = M + (size_t)b * 65536;
  if (!isRHS) {
#pragma unroll
    for (int mi = 0; mi < 4; ++mi) {
      int i = i0 + tr * 4 + mi;
      float4 add = *(const float4*)&Lm[(size_t)i * 256 + j0 + tc * 4];
      acc[mi][0] += add.x; acc[mi][1] += add.y; acc[mi][2] += add.z; acc[mi][3] += add.w;
      float4 v = {acc[mi][0], acc[mi][1], acc[mi][2], acc[mi][3]};
      *(float4*)&Mb[(size_t)i * 256 + j0 + tc * 4] = v;
    }
    if (it != jt) {
      __syncthreads();
#pragma unroll
      for (int mi = 0; mi < 4; ++mi)
#pragma unroll
        for (int cj = 0; cj < 4; ++cj) trbuf[(tc * 4 + cj) * 68 + tr * 4 + mi] = acc[mi][cj];
      __syncthreads();
#pragma unroll
      for (int m = 0; m < 4; ++m) {
        int rr = (t >> 4) + 16 * m, cc4 = (t & 15) * 4;
        float4 v = *(const float4*)&trbuf[rr * 68 + cc4];
        *(float4*)&Mb[(size_t)(j0 + rr) * 256 + i0 + cc4] = v;
      }
    } else if (it == 0) {
      // lookahead: invert M[0][0] -> D0 (Dbuf buffer 0)
      __syncthreads();
#pragma unroll
      for (int mi = 0; mi < 4; ++mi) {
        float4 v = {acc[mi][0], acc[mi][1], acc[mi][2], acc[mi][3]};
        *(float4*)&trbuf[(tr * 4 + mi) * 68 + tc * 4] = v;
      }
      __syncthreads();
      gj64<68>(trbuf, rowbuf, Dbuf + (size_t)b * 4096, t);
    }
  } else {
#pragma unroll
    for (int mi = 0; mi < 4; ++mi) {
      float4 v = {acc[mi][0], acc[mi][1], acc[mi][2], acc[mi][3]};
      *(float4*)&RHS[(size_t)b * 16384 + (size_t)(i0 + tr * 4 + mi) * 64 + tc * 4] = v;
    }
  }
}

// ---------------- one blocked-GJ step (all 16 tiles independent; lookahead GJ of next diag) ----------------
__global__ __launch_bounds__(256) void k_step(float* __restrict__ M, float* __restrict__ Dbuf, int kb) {
  __shared__ float shA[64 * 68];
  __shared__ float shB[64 * 64];
  __shared__ float shC[64 * 64];
  __shared__ float shD[64 * 68];
  __shared__ float rowbuf[256];
  int b = blockIdx.x, u = blockIdx.y;
  int i = u >> 2, j = u & 3;
  int t = threadIdx.x;
  int tr = t >> 4, tc = t & 15;
  float* Mb = M + (size_t)b * 65536;
  const float* Din = Dbuf + (size_t)(kb & 1) * (B * 4096) + (size_t)b * 4096;
  float* Dout = Dbuf + (size_t)((kb + 1) & 1) * (B * 4096) + (size_t)b * 4096;
  bool ik = (i == kb), jk = (j == kb);
  if (ik && jk) {  // diag: M[kb][kb] = D
#pragma unroll
    for (int m = 0; m < 4; ++m) {
      int r = (t >> 4) + 16 * m, c4 = (t & 15) * 4;
      *(float4*)&Mb[(size_t)(kb * 64 + r) * 256 + kb * 64 + c4] = *(const float4*)&Din[r * 64 + c4];
    }
    return;
  }
  float acc[4][4] = {};
  if (ik) {  // rowscale: M[kb][j] = D * M[kb][j]
    load_trans64(shA, 68, Din, 64, t);
    load_direct64(shB, 64, &Mb[(size_t)(kb * 64) * 256 + j * 64], 256, t);
    __syncthreads();
    gemm64<68, 64>(shA, shB, tr, tc, acc);
#pragma unroll
    for (int mi = 0; mi < 4; ++mi) {
      float4 v = {acc[mi][0], acc[mi][1], acc[mi][2], acc[mi][3]};
      *(float4*)&Mb[(size_t)(kb * 64 + tr * 4 + mi) * 256 + j * 64 + tc * 4] = v;
    }
    return;
  }
  if (jk) {  // colscale: M[i][kb] = -M[i][kb] * D
    load_trans64(shA, 68, &Mb[(size_t)(i * 64) * 256 + kb * 64], 256, t);
    load_direct64(shB, 64, Din, 64, t);
    __syncthreads();
    gemm64<68, 64>(shA, shB, tr, tc, acc);
#pragma unroll
    for (int mi = 0; mi < 4; ++mi) {
      float4 v = {-acc[mi][0], -acc[mi][1], -acc[mi][2], -acc[mi][3]};
      *(float4*)&Mb[(size_t)(i * 64 + tr * 4 + mi) * 256 + kb * 64 + tc * 4] = v;
    }
    return;
  }
  // update: T = D * M[kb][j](old); M[i][j] -= M[i][kb](old) * T
  load_trans64(shA, 68, Din, 64, t);
  load_direct64(shB, 64, &Mb[(size_t)(kb * 64) * 256 + j * 64], 256, t);
  load_trans64(shD, 68, &Mb[(size_t)(i * 64) * 256 + kb * 64], 256, t);
  __syncthreads();
  gemm64<68, 64>(shA, shB, tr, tc, acc);
#pragma unroll
  for (int mi = 0; mi < 4; ++mi) {
    float4 v = {acc[mi][0], acc[mi][1], acc[mi][2], acc[mi][3]};
    *(float4*)&shC[(tr * 4 + mi) * 64 + tc * 4] = v;
  }
  __syncthreads();
  float acc2[4][4] = {};
  gemm64<68, 64>(shD, shC, tr, tc, acc2);
  bool la = (kb < 3) && (i == kb + 1) && (j == kb + 1);
#pragma unroll
  for (int mi = 0; mi < 4; ++mi) {
    size_t off = (size_t)(i * 64 + tr * 4 + mi) * 256 + j * 64 + tc * 4;
    float4 old = *(const float4*)&Mb[off];
    float4 v = {old.x - acc2[mi][0], old.y - acc2[mi][1], old.z - acc2[mi][2], old.w - acc2[mi][3]};
    *(float4*)&Mb[off] = v;
    if (la) *(float4*)&shB[(tr * 4 + mi) * 64 + tc * 4] = v;
  }
  if (la) {  // invert the freshly-updated next diag block -> D_{kb+1}
    __syncthreads();
    gj64<64>(shB, rowbuf, Dout, t);
  }
}

// ---------------- postK: PK[b] = Minv[b] @ (RHS[b] + LK) ----------------
__global__ __launch_bounds__(256) void k_postK(const float* __restrict__ Minv, const float* __restrict__ RHS,
                                               const float* __restrict__ LK, float* __restrict__ PK) {
  int b = blockIdx.x, it = blockIdx.y;
  int i0 = it * 64;
  const float* A = Minv + (size_t)b * 65536;
  const float* G = RHS + (size_t)b * 16384;
  __shared__ float At[16][68];
  __shared__ float Bs[16][64];
  float acc[4][4] = {};
  int t = threadIdx.x, tr = t >> 4, tc = t & 15;
  int ar = t >> 2, ac4 = (t & 3) * 4;
  int br = t >> 6, bc = t & 63;
  for (int ks = 0; ks < 256; ks += 16) {
    __syncthreads();
    float4 av = *(const float4*)&A[(size_t)(i0 + ar) * 256 + ks + ac4];
    At[ac4 + 0][ar] = av.x; At[ac4 + 1][ar] = av.y; At[ac4 + 2][ar] = av.z; At[ac4 + 3][ar] = av.w;
#pragma unroll
    for (int m = 0; m < 4; ++m) {
      int kk = ks + br + 4 * m;
      Bs[br + 4 * m][bc] = G[(size_t)kk * 64 + bc] + LK[(size_t)kk * 64 + bc];
    }
    __syncthreads();
#pragma unroll
    for (int kk = 0; kk < 16; ++kk) {
      float4 a4 = *(const float4*)&At[kk][tr * 4];
      float4 b4 = *(const float4*)&Bs[kk][tc * 4];
      fma4x4(a4, b4, acc);
    }
  }
#pragma unroll
  for (int mi = 0; mi < 4; ++mi) {
    float4 v = {acc[mi][0], acc[mi][1], acc[mi][2], acc[mi][3]};
    *(float4*)&PK[(size_t)b * 16384 + (size_t)(i0 + tr * 4 + mi) * 64 + tc * 4] = v;
  }
}

// ---------------- mu (z==4) + spread (z<4) ----------------
__global__ __launch_bounds__(256) void k_muspread(const float* __restrict__ phi_q, const float* __restrict__ Minv,
                                                  const float* __restrict__ PK, float* __restrict__ mu,
                                                  float* __restrict__ spread) {
  int b = blockIdx.x, it = blockIdx.y, z = blockIdx.z;
  const float* A = phi_q + (size_t)b * Q * I;
  __shared__ float At[16][68];
  __shared__ float Bs[16][64];
  float acc[4][4] = {};
  int t = threadIdx.x, tr = t >> 4, tc = t & 15;
  int ar = t >> 2, ac4 = (t & 3) * 4;
  int br = t >> 6, bc = t & 63;
  int q0 = it * 64;
  if (z == 4) {
    const float* Bm = PK + (size_t)b * 16384;
    for (int ks = 0; ks < 256; ks += 16) {
      __syncthreads();
      float4 av = *(const float4*)&A[(size_t)(q0 + ar) * 256 + ks + ac4];
      At[ac4 + 0][ar] = av.x; At[ac4 + 1][ar] = av.y; At[ac4 + 2][ar] = av.z; At[ac4 + 3][ar] = av.w;
#pragma unroll
      for (int m = 0; m < 4; ++m) Bs[br + 4 * m][bc] = Bm[(size_t)(ks + br + 4 * m) * 64 + bc];
      __syncthreads();
#pragma unroll
      for (int kk = 0; kk < 16; ++kk) {
        float4 a4 = *(const float4*)&At[kk][tr * 4];
        float4 b4 = *(const float4*)&Bs[kk][tc * 4];
        fma4x4(a4, b4, acc);
      }
    }
#pragma unroll
    for (int mi = 0; mi < 4; ++mi) {
      float4 v = {acc[mi][0], acc[mi][1], acc[mi][2], acc[mi][3]};
      *(float4*)&mu[(size_t)b * Q * O + (size_t)(q0 + tr * 4 + mi) * 64 + tc * 4] = v;
    }
  } else {
    int j0 = z * 64;
    const float* Bm = Minv + (size_t)b * 65536;
    for (int ks = 0; ks < 256; ks += 16) {
      __syncthreads();
      float4 av = *(const float4*)&A[(size_t)(q0 + ar) * 256 + ks + ac4];
      At[ac4 + 0][ar] = av.x; At[ac4 + 1][ar] = av.y; At[ac4 + 2][ar] = av.z; At[ac4 + 3][ar] = av.w;
#pragma unroll
      for (int m = 0; m < 4; ++m) Bs[br + 4 * m][bc] = Bm[(size_t)(ks + br + 4 * m) * 256 + j0 + bc];
      __syncthreads();
#pragma unroll
      for (int kk = 0; kk < 16; ++kk) {
        float4 a4 = *(const float4*)&At[kk][tr * 4];
        float4 b4 = *(const float4*)&Bs[kk][tc * 4];
        fma4x4(a4, b4, acc);
      }
    }
    float rs[4];
#pragma unroll
    for (int mi = 0; mi < 4; ++mi) {
      int qrow = q0 + tr * 4 + mi;
      float4 pv = *(const float4*)&A[(size_t)qrow * 256 + j0 + tc * 4];
      rs[mi] = acc[mi][0] * pv.x + acc[mi][1] * pv.y + acc[mi][2] * pv.z + acc[mi][3] * pv.w;
    }
#pragma unroll
    for (int off = 1; off < 16; off <<= 1) {
#pragma unroll
      for (int mi = 0; mi < 4; ++mi) rs[mi] += __shfl_xor(rs[mi], off);
    }
    if (tc == 0) {
#pragma unroll
      for (int mi = 0; mi < 4; ++mi) atomicAdd(&spread[(size_t)b * Q + q0 + tr * 4 + mi], rs[mi]);
    }
  }
}

// ---------------- sig fill (blocks < 65536) + nll partial (64 blocks) ----------------
__global__ __launch_bounds__(256) void k_signll(const float* __restrict__ spread, float4* __restrict__ sig,
                                                const float* __restrict__ yq, const float* __restrict__ mu,
                                                float* __restrict__ nllacc) {
  int t = threadIdx.x;
  if (blockIdx.x < 65536) {
    size_t idx = (size_t)blockIdx.x * 256 + t;
    int p4 = (int)(idx & 15);
    int o = (int)((idx >> 4) & 63);
    size_t bq = idx >> 10;
    float sv = spread[bq] * SIG_EPS;
    float4 v;
    v.x = (p4 * 4 + 0 == o) ? sv : 0.f;
    v.y = (p4 * 4 + 1 == o) ? sv : 0.f;
    v.z = (p4 * 4 + 2 == o) ? sv : 0.f;
    v.w = (p4 * 4 + 3 == o) ? sv : 0.f;
    sig[idx] = v;
  } else {
    int bq = (blockIdx.x - 65536) * 256 + t;
    float sp = spread[bq];
    const float4* yv = (const float4*)(yq + (size_t)bq * 64);
    const float4* mv = (const float4*)(mu + (size_t)bq * 64);
    float ssd = 0.f;
#pragma unroll
    for (int i = 0; i < 16; ++i) {
      float4 a = yv[i], b = mv[i];
      float dx = a.x - b.x, dy = a.y - b.y, dz = a.z - b.z, dw = a.w - b.w;
      ssd += dx * dx + dy * dy + dz * dz + dw * dw;
    }
    float quadf = ssd / (sp * SIG_EPS);
    float ld = 64.0f * (logf(sp) + LOG_SIG_EPS);
    float val = (ld + quadf) * (1.0f / 16384.0f);
#pragma unroll
    for (int off = 32; off; off >>= 1) val += __shfl_down(val, off);
    if ((t & 63) == 0) atomicAdd(nllacc, val);
  }
}

__global__ void k_fin(const float* __restrict__ nllacc, float* __restrict__ out) {
  if (threadIdx.x == 0 && blockIdx.x == 0) out[0] = nllacc[0];
}

extern "C" void kernel_launch(void* const* d_in, const int* in_sizes, int n_in, void* d_out, int out_size,
                              void* d_ws, size_t ws_size, hipStream_t stream) {
  const float* phi_s = (const float*)d_in[0];
  const float* y_s = (const float*)d_in[1];
  const float* phi_q = (const float*)d_in[2];
  const float* y_q = (const float*)d_in[3];
  const float* Km = (const float*)d_in[4];
  const float* La = (const float*)d_in[5];

  float* ws = (float*)d_ws;
  float* Lm = ws + WS_L;
  float* T1 = ws + WS_T1;
  float* LKm = ws + WS_LK;
  float* Mbuf = ws + WS_M;
  float* RHSb = ws + WS_RHS;
  float* Dbuf = ws + WS_D;
  float* PKb = ws + WS_PK;
  float* spread = ws + WS_SP;
  float* nllacc = ws + WS_NLL;

  float* out_mu = (float*)d_out;
  float* out_sig = out_mu + OUT_MU_ELEMS;
  float* out_nll = out_mu + OUT_NLL_IDX;

  k_pre1<<<84, 256, 0, stream>>>(La, Km, Lm, T1, spread, nllacc);
  k_gram<<<dim3(B, 15), 256, 0, stream>>>(phi_s, y_s, Lm, La, T1, Mbuf, RHSb, LKm, Dbuf);
  for (int kb = 0; kb < 4; ++kb) k_step<<<dim3(B, 16), 256, 0, stream>>>(Mbuf, Dbuf, kb);
  k_postK<<<dim3(B, 4), 256, 0, stream>>>(Mbuf, RHSb, LKm, PKb);
  k_muspread<<<dim3(B, 8, 5), 256, 0, stream>>>(phi_q, Mbuf, PKb, out_mu, spread);
  k_signll<<<65600, 256, 0, stream>>>(spread, (float4*)out_sig, y_q, out_mu, nllacc);
  k_fin<<<1, 64, 0, stream>>>(nllacc, out_nll);
}